// Round 15
// baseline (388.629 us; speedup 1.0000x reference)
//
#include <hip/hip_runtime.h>
#include <hip/hip_bf16.h>

// SGConv (K=2) on MI355X.
// R4: MFMA matmul. R6: bucket build + counting sort -> CSR gather hops.
// R7: bf16 z-tables. R8/R9: gather unroll + fused hop2/log_softmax.
// R12: z rows padded to 128B (one line per gather). 310.7us.
// R13 FAILED: degree-perm destroyed sequential row_ptr/csr/zout access.
// R14: R12 base + per-row SORTED neighbor lists (LDS insertion sort in
//      k_sort). Sorted rows => all waves walk the z table monotonically =>
//      gathers hit XCD-L2 (active window few MB) instead of LLC.
//      ETILE back to 8192 (391 blocks for bhist/part occupancy).

#define TPB 256
#define ETILE 8192                 // edges per partition block
#define ZS 64                      // padded z row: 64 bf16 = 128 B
#define STASH 10240                // LDS sort stash (ints); bucket mean 8184

typedef __attribute__((ext_vector_type(8))) short short8v;   // bf16x8
typedef __attribute__((ext_vector_type(4))) float f32x4;

__device__ inline short f2bf(float f) {            // RNE f32->bf16
    unsigned u = __float_as_uint(f);
    unsigned r = (u + 0x7fffu + ((u >> 16) & 1u)) >> 16;
    return (short)r;
}
__device__ inline float bf2f(short s) {
    return __uint_as_float(((unsigned)(unsigned short)s) << 16);
}

// ---- W -> Wb (48x512 bf16) and (block 0) zero bcnt ---------------------
__global__ void k_wconv(const float* __restrict__ W, short* __restrict__ Wb,
                        int* __restrict__ bcnt, int nb) {
    if (blockIdx.x == 0)
        for (int i = threadIdx.x; i < nb; i += TPB) bcnt[i] = 0;
    int idx = blockIdx.x * TPB + threadIdx.x;    // 0..24575
    int c = idx >> 9, k = idx & 511;
    float v = (c < 40) ? W[c * 512 + k] : 0.f;
    Wb[idx] = f2bf(v);
}

// ---- per-bucket edge histogram (bucket = dst>>8) -----------------------
__global__ __launch_bounds__(TPB) void k_bhist(
    const int* __restrict__ dst, int* __restrict__ bcnt, int E, int nb) {
    __shared__ int h[512];
    int t = threadIdx.x;
    for (int i = t; i < nb; i += TPB) h[i] = 0;
    __syncthreads();
    int e0 = blockIdx.x * ETILE;
    int e1 = min(e0 + ETILE, E);
    for (int e = e0 + t; e < e1; e += TPB)
        atomicAdd(&h[dst[e] >> 8], 1);
    __syncthreads();
    for (int i = t; i < nb; i += TPB)
        if (h[i]) atomicAdd(&bcnt[i], h[i]);
}

// ---- 391-entry exclusive scan -> boff, bcur (single block) -------------
__global__ __launch_bounds__(512) void k_boff(
    const int* __restrict__ bcnt, int* __restrict__ boff,
    int* __restrict__ bcur, int nb) {
    __shared__ int s[512];
    int t = threadIdx.x;
    int own = (t < nb) ? bcnt[t] : 0;
    s[t] = own;
    __syncthreads();
    for (int off = 1; off < 512; off <<= 1) {
        int v = (t >= off) ? s[t - off] : 0;
        __syncthreads();
        s[t] += v;
        __syncthreads();
    }
    if (t < nb) {
        int ex = s[t] - own;
        boff[t] = ex;
        bcur[t] = ex;
        if (t == nb - 1) boff[nb] = s[t];
    }
}

// ---- block-aggregated bucket partition (no stash: dst read twice) ------
__global__ __launch_bounds__(TPB) void k_part(
    const int* __restrict__ src, const int* __restrict__ dst,
    int* __restrict__ bcur, int* __restrict__ pairs, int E, int nb) {
    __shared__ int hist[512], base[512];
    int t = threadIdx.x;
    for (int i = t; i < nb; i += TPB) hist[i] = 0;
    __syncthreads();
    int e0 = blockIdx.x * ETILE;
    int e1 = min(e0 + ETILE, E);
    for (int e = e0 + t; e < e1; e += TPB)
        atomicAdd(&hist[dst[e] >> 8], 1);
    __syncthreads();
    for (int i = t; i < nb; i += TPB) {
        base[i] = hist[i] ? atomicAdd(&bcur[i], hist[i]) : 0;
        hist[i] = 0;                         // reuse as local cursor
    }
    __syncthreads();
    for (int e = e0 + t; e < e1; e += TPB) { // dst re-read: L2-warm
        int d = dst[e];
        int b = d >> 8;
        int pos = base[b] + atomicAdd(&hist[b], 1);
        pairs[pos] = ((d & 255) << 20) | src[e];   // src < 2^20
    }
}

// ---- per-bucket counting sort + per-row ascending src sort -------------
// Emits csr (rows sorted by src), row_ptr, dinv. Sorted rows make the hop
// gathers walk z monotonically -> L2-resident working window.
__global__ __launch_bounds__(TPB) void k_sort(
    const int* __restrict__ pairs, const int* __restrict__ boff,
    int* __restrict__ csr, int* __restrict__ row_ptr, float* __restrict__ dinv,
    int N, int nb) {
    __shared__ int B[STASH];
    __shared__ int hist[256], excl[256], lcur[256];
    int b = blockIdx.x, t = threadIdx.x;
    hist[t] = 0;
    __syncthreads();
    int beg = boff[b], end = boff[b + 1];
    int cnt = end - beg;
    for (int j = beg + t; j < end; j += TPB)
        atomicAdd(&hist[pairs[j] >> 20], 1);
    __syncthreads();
    int own = hist[t];
    excl[t] = own;
    __syncthreads();
    for (int off = 1; off < 256; off <<= 1) {
        int v = (t >= off) ? excl[t - off] : 0;
        __syncthreads();
        excl[t] += v;
        __syncthreads();
    }
    int node = (b << 8) + t;
    if (node < N) {
        row_ptr[node] = beg + excl[t] - own;   // global exclusive offset
        dinv[node] = rsqrtf((float)(own + 1)); // +1 self-loop
    }
    lcur[t] = 0;
    __syncthreads();
    if (cnt <= STASH) {
        // scatter into LDS at local offsets
        for (int j = beg + t; j < end; j += TPB) {
            int u = pairs[j];
            int dl = u >> 20;
            int pos = (excl[dl] - hist[dl]) + atomicAdd(&lcur[dl], 1);
            B[pos] = u & 0xFFFFF;
        }
        __syncthreads();
        // per-row insertion sort (ascending src) in LDS
        int s0 = excl[t] - own, e2 = excl[t];
        for (int i = s0 + 1; i < e2; ++i) {
            int key = B[i];
            int j2 = i - 1;
            while (j2 >= s0 && B[j2] > key) { B[j2 + 1] = B[j2]; --j2; }
            B[j2 + 1] = key;
        }
        __syncthreads();
        // coalesced write out
        for (int j = t; j < cnt; j += TPB) csr[beg + j] = B[j];
    } else {
        // fallback (unsorted rows still correct)
        for (int j = beg + t; j < end; j += TPB) {
            int u = pairs[j];
            int dl = u >> 20;
            int pos = beg + (excl[dl] - hist[dl]) + atomicAdd(&lcur[dl], 1);
            csr[pos] = u & 0xFFFFF;
        }
    }
    if (b == nb - 1 && t == 0) row_ptr[N] = end;
}

// ---- z0 = bf16( dinv .* (x @ W^T) ), row stride 64, cols 40..63 = 0 ----
__global__ __launch_bounds__(TPB) void k_matmul_mfma(
    const float* __restrict__ x, const short* __restrict__ Wb,
    const float* __restrict__ dinv, short* __restrict__ z, int N) {
    int wid  = threadIdx.x >> 6;
    int lane = threadIdx.x & 63;
    int rbase = blockIdx.x * 64 + wid * 16;
    if (rbase >= N) return;
    int arow   = rbase + (lane & 15);
    int aclamp = min(arow, N - 1);
    int koff   = (lane >> 4) * 8;
    const float* xrow = x + (size_t)aclamp * 512 + koff;
    const short* wb   = Wb + (lane & 15) * 512 + koff;

    f32x4 acc0 = {0.f,0.f,0.f,0.f}, acc1 = {0.f,0.f,0.f,0.f}, acc2 = {0.f,0.f,0.f,0.f};
    for (int ks = 0; ks < 16; ++ks) {
        int k0 = ks * 32;
        float4 f0 = *reinterpret_cast<const float4*>(xrow + k0);
        float4 f1 = *reinterpret_cast<const float4*>(xrow + k0 + 4);
        short8v a;
        a[0] = f2bf(f0.x); a[1] = f2bf(f0.y); a[2] = f2bf(f0.z); a[3] = f2bf(f0.w);
        a[4] = f2bf(f1.x); a[5] = f2bf(f1.y); a[6] = f2bf(f1.z); a[7] = f2bf(f1.w);
        short8v b0 = *reinterpret_cast<const short8v*>(wb + k0);
        short8v b1 = *reinterpret_cast<const short8v*>(wb + 16 * 512 + k0);
        short8v b2 = *reinterpret_cast<const short8v*>(wb + 32 * 512 + k0);
        acc0 = __builtin_amdgcn_mfma_f32_16x16x32_bf16(a, b0, acc0, 0, 0, 0);
        acc1 = __builtin_amdgcn_mfma_f32_16x16x32_bf16(a, b1, acc1, 0, 0, 0);
        acc2 = __builtin_amdgcn_mfma_f32_16x16x32_bf16(a, b2, acc2, 0, 0, 0);
    }
    int col = lane & 15;
    int rw  = rbase + (lane >> 4) * 4;
#pragma unroll
    for (int reg = 0; reg < 4; ++reg) {
        int r = rw + reg;
        if (r < N) {
            float di = dinv[r];
            short* zr = z + (size_t)r * ZS;
            zr[col]      = f2bf(di * acc0[reg]);
            zr[16 + col] = f2bf(di * acc1[reg]);
            zr[32 + col] = f2bf(di * acc2[reg]);   // cols 40-47: Wb rows zero
            zr[48 + col] = 0;                      // cols 48-63: explicit zero
        }
    }
}

// ---- shared gather body: acc[8] += sum_{s in csr[beg..end)} zin[s] -----
// 8 lanes/node; each lane owns one 16B chunk of the 128B (one-line) row.
// Rows are src-ascending -> monotone walk of z (L2-friendly).
__device__ inline void gather_acc(
    const short8v* __restrict__ Z, const int* __restrict__ csr,
    int beg, int end, int c8, float acc[8]) {
    int j = beg;
    for (; j + 4 <= end; j += 4) {               // 4 gathers in flight
        int s0 = csr[j], s1 = csr[j+1], s2 = csr[j+2], s3 = csr[j+3];
        short8v v0 = Z[s0 * 8 + c8];
        short8v v1 = Z[s1 * 8 + c8];
        short8v v2 = Z[s2 * 8 + c8];
        short8v v3 = Z[s3 * 8 + c8];
#pragma unroll
        for (int k = 0; k < 8; ++k)
            acc[k] += (bf2f(v0[k]) + bf2f(v1[k])) + (bf2f(v2[k]) + bf2f(v3[k]));
    }
    for (; j < end; ++j) {
        short8v v = Z[csr[j] * 8 + c8];
#pragma unroll
        for (int k = 0; k < 8; ++k) acc[k] += bf2f(v[k]);
    }
}

// ---- hop1: z1 = bf16( dinv^2 .* (A z0) ), 8 lanes/node -----------------
__global__ __launch_bounds__(TPB) void k_hop1(
    const int* __restrict__ csr, const int* __restrict__ row_ptr,
    const float* __restrict__ dinv, const short* __restrict__ zin,
    short* __restrict__ zout, int N) {
    int t = blockIdx.x * TPB + threadIdx.x;
    int node = t >> 3;
    int c8 = t & 7;
    if (node >= N) return;
    const short8v* Z = reinterpret_cast<const short8v*>(zin);
    short8v sv = Z[node * 8 + c8];             // self-loop term
    float acc[8];
#pragma unroll
    for (int k = 0; k < 8; ++k) acc[k] = bf2f(sv[k]);
    gather_acc(Z, csr, row_ptr[node], row_ptr[node + 1], c8, acc);
    float dd = dinv[node];
    float sc = dd * dd;
    short8v o;
#pragma unroll
    for (int k = 0; k < 8; ++k) o[k] = f2bf(sc * acc[k]);
    reinterpret_cast<short8v*>(zout)[node * 8 + c8] = o;
}

// ---- hop2 fused with bias + log_softmax; 8 lanes/node, 8 nodes/wave ----
__global__ __launch_bounds__(TPB) void k_hop2_lsm(
    const int* __restrict__ csr, const int* __restrict__ row_ptr,
    const float* __restrict__ dinv, const short* __restrict__ zin,
    const float* __restrict__ bias, float* __restrict__ out, int N) {
    int t = blockIdx.x * TPB + threadIdx.x;
    int node = t >> 3;
    int c8 = t & 7;
    if (node >= N) return;
    const short8v* Z = reinterpret_cast<const short8v*>(zin);
    short8v sv = Z[node * 8 + c8];
    float acc[8];
#pragma unroll
    for (int k = 0; k < 8; ++k) acc[k] = bf2f(sv[k]);
    gather_acc(Z, csr, row_ptr[node], row_ptr[node + 1], c8, acc);
    float dd = dinv[node];

    float v[8];
    float lm = -1e30f;
    bool live = (c8 < 5);                      // cols 0..39 only
    if (live) {
#pragma unroll
        for (int k = 0; k < 8; ++k) {
            v[k] = dd * acc[k] + bias[c8 * 8 + k];
            lm = fmaxf(lm, v[k]);
        }
    }
    // butterfly over the 8-lane group (shfl_xor 1,2,4 stays in-group)
    float gm = lm;
    gm = fmaxf(gm, __shfl_xor(gm, 1));
    gm = fmaxf(gm, __shfl_xor(gm, 2));
    gm = fmaxf(gm, __shfl_xor(gm, 4));
    float ls = 0.f;
    if (live) {
#pragma unroll
        for (int k = 0; k < 8; ++k) ls += __expf(v[k] - gm);
    }
    ls += __shfl_xor(ls, 1);
    ls += __shfl_xor(ls, 2);
    ls += __shfl_xor(ls, 4);
    if (live) {
        float lse = gm + __logf(ls);
        float* op = out + (size_t)node * 40 + c8 * 8;
        *reinterpret_cast<float4*>(op)     = make_float4(v[0]-lse, v[1]-lse, v[2]-lse, v[3]-lse);
        *reinterpret_cast<float4*>(op + 4) = make_float4(v[4]-lse, v[5]-lse, v[6]-lse, v[7]-lse);
    }
}

extern "C" void kernel_launch(void* const* d_in, const int* in_sizes, int n_in,
                              void* d_out, int out_size, void* d_ws, size_t ws_size,
                              hipStream_t stream) {
    const float* x  = (const float*)d_in[0];
    const int*   ei = (const int*)d_in[1];
    const float* W  = (const float*)d_in[2];
    const float* b  = (const float*)d_in[3];
    float* out = (float*)d_out;

    const int N = in_sizes[0] / 512;     // 100000
    const int E = in_sizes[1] / 2;       // 3200000
    const int* src = ei;                 // edge_index[0]
    const int* dst = ei + E;             // edge_index[1]
    const int nb = (N + 255) >> 8;       // 391 buckets

    // workspace: z0 [N*64 bf16 = 12.8MB] | z1/pairs alias [12.8MB] | csr [E]
    //   | bcnt [nb] | boff [nb+1] | bcur [nb] | row_ptr [N+1] | dinv [N]
    //   | Wb [48*512 bf16]   (pairs dead before hop1 writes z1)
    short* z0      = (short*)d_ws;
    short* z1      = z0 + (size_t)N * ZS;
    int*   pairs   = (int*)z1;                 // alias: dead after k_sort
    int*   csr     = (int*)(z1 + (size_t)N * ZS);
    int*   bcnt    = csr + E;
    int*   boff    = bcnt + nb;
    int*   bcur    = boff + nb + 1;
    int*   row_ptr = bcur + nb;
    float* dinv    = (float*)(row_ptr + N + 1);
    short* Wb      = (short*)(dinv + N);

    int gT  = (E + ETILE - 1) / ETILE;   // 391 edge tiles
    int gM  = (N + 63) / 64;
    int gH  = (N * 8 + TPB - 1) / TPB;   // 3125

    k_wconv<<<(48 * 512) / TPB, TPB, 0, stream>>>(W, Wb, bcnt, nb);
    k_bhist<<<gT, TPB, 0, stream>>>(dst, bcnt, E, nb);
    k_boff<<<1, 512, 0, stream>>>(bcnt, boff, bcur, nb);
    k_part<<<gT, TPB, 0, stream>>>(src, dst, bcur, pairs, E, nb);
    k_sort<<<nb, TPB, 0, stream>>>(pairs, boff, csr, row_ptr, dinv, N, nb);

    k_matmul_mfma<<<gM, TPB, 0, stream>>>(x, Wb, dinv, z0, N);

    k_hop1<<<gH, TPB, 0, stream>>>(csr, row_ptr, dinv, z0, z1, N);
    k_hop2_lsm<<<gH, TPB, 0, stream>>>(csr, row_ptr, dinv, z1, b, out, N);
}

// Round 16
// 296.436 us; speedup vs baseline: 1.3110x; 1.3110x over previous
//
#include <hip/hip_runtime.h>
#include <hip/hip_bf16.h>

// SGConv (K=2) on MI355X.
// R4: MFMA matmul. R6: bucket build + counting sort -> CSR gather hops.
// R7: bf16 z-tables. R8/R9: gather unroll + fused hop2/log_softmax.
// R12: z rows padded to 128B (one line per gather). 310.7us.
// R14: sorted neighbor rows help hops (-37us) but insertion sort cost +115us.
// R15: sort rows via fully-unrolled REGISTER bitonic network (64-wide,
//      sentinel-padded, static indices -> no scratch, no divergence, no LDS
//      traffic). ETILE back to 16384 (R12 config).

#define TPB 256
#define ETILE 16384                // edges per partition block
#define ZS 64                      // padded z row: 64 bf16 = 128 B
#define STASH 10240                // LDS sort stash (ints); bucket mean 8184

typedef __attribute__((ext_vector_type(8))) short short8v;   // bf16x8
typedef __attribute__((ext_vector_type(4))) float f32x4;

__device__ inline short f2bf(float f) {            // RNE f32->bf16
    unsigned u = __float_as_uint(f);
    unsigned r = (u + 0x7fffu + ((u >> 16) & 1u)) >> 16;
    return (short)r;
}
__device__ inline float bf2f(short s) {
    return __uint_as_float(((unsigned)(unsigned short)s) << 16);
}

// ---- fully-unrolled 64-element bitonic sort on a register array --------
// Same static CE schedule on every lane: no divergence, indices all
// compile-time constants (stays in VGPRs, rule #20 safe).
__device__ inline void bitonic64(int a[64]) {
#pragma unroll
    for (int k = 2; k <= 64; k <<= 1) {
#pragma unroll
        for (int j = k >> 1; j > 0; j >>= 1) {
#pragma unroll
            for (int i = 0; i < 64; ++i) {
                int l = i ^ j;
                if (l > i) {
                    int lo = min(a[i], a[l]);
                    int hi = max(a[i], a[l]);
                    bool up = ((i & k) == 0);
                    a[i] = up ? lo : hi;
                    a[l] = up ? hi : lo;
                }
            }
        }
    }
}

// ---- W -> Wb (48x512 bf16) and (block 0) zero bcnt ---------------------
__global__ void k_wconv(const float* __restrict__ W, short* __restrict__ Wb,
                        int* __restrict__ bcnt, int nb) {
    if (blockIdx.x == 0)
        for (int i = threadIdx.x; i < nb; i += TPB) bcnt[i] = 0;
    int idx = blockIdx.x * TPB + threadIdx.x;    // 0..24575
    int c = idx >> 9, k = idx & 511;
    float v = (c < 40) ? W[c * 512 + k] : 0.f;
    Wb[idx] = f2bf(v);
}

// ---- per-bucket edge histogram (bucket = dst>>8) -----------------------
__global__ __launch_bounds__(TPB) void k_bhist(
    const int* __restrict__ dst, int* __restrict__ bcnt, int E, int nb) {
    __shared__ int h[512];
    int t = threadIdx.x;
    for (int i = t; i < nb; i += TPB) h[i] = 0;
    __syncthreads();
    int e0 = blockIdx.x * ETILE;
    int e1 = min(e0 + ETILE, E);
    for (int e = e0 + t; e < e1; e += TPB)
        atomicAdd(&h[dst[e] >> 8], 1);
    __syncthreads();
    for (int i = t; i < nb; i += TPB)
        if (h[i]) atomicAdd(&bcnt[i], h[i]);
}

// ---- 391-entry exclusive scan -> boff, bcur (single block) -------------
__global__ __launch_bounds__(512) void k_boff(
    const int* __restrict__ bcnt, int* __restrict__ boff,
    int* __restrict__ bcur, int nb) {
    __shared__ int s[512];
    int t = threadIdx.x;
    int own = (t < nb) ? bcnt[t] : 0;
    s[t] = own;
    __syncthreads();
    for (int off = 1; off < 512; off <<= 1) {
        int v = (t >= off) ? s[t - off] : 0;
        __syncthreads();
        s[t] += v;
        __syncthreads();
    }
    if (t < nb) {
        int ex = s[t] - own;
        boff[t] = ex;
        bcur[t] = ex;
        if (t == nb - 1) boff[nb] = s[t];
    }
}

// ---- block-aggregated bucket partition (no stash: dst read twice) ------
__global__ __launch_bounds__(TPB) void k_part(
    const int* __restrict__ src, const int* __restrict__ dst,
    int* __restrict__ bcur, int* __restrict__ pairs, int E, int nb) {
    __shared__ int hist[512], base[512];
    int t = threadIdx.x;
    for (int i = t; i < nb; i += TPB) hist[i] = 0;
    __syncthreads();
    int e0 = blockIdx.x * ETILE;
    int e1 = min(e0 + ETILE, E);
    for (int e = e0 + t; e < e1; e += TPB)
        atomicAdd(&hist[dst[e] >> 8], 1);
    __syncthreads();
    for (int i = t; i < nb; i += TPB) {
        base[i] = hist[i] ? atomicAdd(&bcur[i], hist[i]) : 0;
        hist[i] = 0;                         // reuse as local cursor
    }
    __syncthreads();
    for (int e = e0 + t; e < e1; e += TPB) { // dst re-read: L2-warm
        int d = dst[e];
        int b = d >> 8;
        int pos = base[b] + atomicAdd(&hist[b], 1);
        pairs[pos] = ((d & 255) << 20) | src[e];   // src < 2^20
    }
}

// ---- per-bucket counting sort + per-row register-bitonic src sort ------
__global__ __launch_bounds__(TPB) void k_sort(
    const int* __restrict__ pairs, const int* __restrict__ boff,
    int* __restrict__ csr, int* __restrict__ row_ptr, float* __restrict__ dinv,
    int N, int nb) {
    __shared__ int B[STASH];
    __shared__ int hist[256], excl[256], lcur[256];
    int b = blockIdx.x, t = threadIdx.x;
    hist[t] = 0;
    __syncthreads();
    int beg = boff[b], end = boff[b + 1];
    int cnt = end - beg;
    for (int j = beg + t; j < end; j += TPB)
        atomicAdd(&hist[pairs[j] >> 20], 1);
    __syncthreads();
    int own = hist[t];
    excl[t] = own;
    __syncthreads();
    for (int off = 1; off < 256; off <<= 1) {
        int v = (t >= off) ? excl[t - off] : 0;
        __syncthreads();
        excl[t] += v;
        __syncthreads();
    }
    int node = (b << 8) + t;
    if (node < N) {
        row_ptr[node] = beg + excl[t] - own;   // global exclusive offset
        dinv[node] = rsqrtf((float)(own + 1)); // +1 self-loop
    }
    lcur[t] = 0;
    __syncthreads();
    if (cnt <= STASH) {
        // scatter into LDS at local offsets (rows packed contiguously)
        for (int j = beg + t; j < end; j += TPB) {
            int u = pairs[j];
            int dl = u >> 20;
            int pos = (excl[dl] - hist[dl]) + atomicAdd(&lcur[dl], 1);
            B[pos] = u & 0xFFFFF;
        }
        __syncthreads();
        // per-row sort: registers + static bitonic network
        int s0 = excl[t] - own;
        if (own >= 2 && own <= 64) {
            int r[64];
#pragma unroll
            for (int i = 0; i < 64; ++i)
                r[i] = (i < own) ? B[s0 + i] : 0x7FFFFFFF;
            bitonic64(r);
#pragma unroll
            for (int i = 0; i < 64; ++i)
                if (i < own) B[s0 + i] = r[i];
        }
        __syncthreads();
        // coalesced write out
        for (int j = t; j < cnt; j += TPB) csr[beg + j] = B[j];
    } else {
        // fallback (unsorted rows still correct)
        for (int j = beg + t; j < end; j += TPB) {
            int u = pairs[j];
            int dl = u >> 20;
            int pos = beg + (excl[dl] - hist[dl]) + atomicAdd(&lcur[dl], 1);
            csr[pos] = u & 0xFFFFF;
        }
    }
    if (b == nb - 1 && t == 0) row_ptr[N] = end;
}

// ---- z0 = bf16( dinv .* (x @ W^T) ), row stride 64, cols 40..63 = 0 ----
__global__ __launch_bounds__(TPB) void k_matmul_mfma(
    const float* __restrict__ x, const short* __restrict__ Wb,
    const float* __restrict__ dinv, short* __restrict__ z, int N) {
    int wid  = threadIdx.x >> 6;
    int lane = threadIdx.x & 63;
    int rbase = blockIdx.x * 64 + wid * 16;
    if (rbase >= N) return;
    int arow   = rbase + (lane & 15);
    int aclamp = min(arow, N - 1);
    int koff   = (lane >> 4) * 8;
    const float* xrow = x + (size_t)aclamp * 512 + koff;
    const short* wb   = Wb + (lane & 15) * 512 + koff;

    f32x4 acc0 = {0.f,0.f,0.f,0.f}, acc1 = {0.f,0.f,0.f,0.f}, acc2 = {0.f,0.f,0.f,0.f};
    for (int ks = 0; ks < 16; ++ks) {
        int k0 = ks * 32;
        float4 f0 = *reinterpret_cast<const float4*>(xrow + k0);
        float4 f1 = *reinterpret_cast<const float4*>(xrow + k0 + 4);
        short8v a;
        a[0] = f2bf(f0.x); a[1] = f2bf(f0.y); a[2] = f2bf(f0.z); a[3] = f2bf(f0.w);
        a[4] = f2bf(f1.x); a[5] = f2bf(f1.y); a[6] = f2bf(f1.z); a[7] = f2bf(f1.w);
        short8v b0 = *reinterpret_cast<const short8v*>(wb + k0);
        short8v b1 = *reinterpret_cast<const short8v*>(wb + 16 * 512 + k0);
        short8v b2 = *reinterpret_cast<const short8v*>(wb + 32 * 512 + k0);
        acc0 = __builtin_amdgcn_mfma_f32_16x16x32_bf16(a, b0, acc0, 0, 0, 0);
        acc1 = __builtin_amdgcn_mfma_f32_16x16x32_bf16(a, b1, acc1, 0, 0, 0);
        acc2 = __builtin_amdgcn_mfma_f32_16x16x32_bf16(a, b2, acc2, 0, 0, 0);
    }
    int col = lane & 15;
    int rw  = rbase + (lane >> 4) * 4;
#pragma unroll
    for (int reg = 0; reg < 4; ++reg) {
        int r = rw + reg;
        if (r < N) {
            float di = dinv[r];
            short* zr = z + (size_t)r * ZS;
            zr[col]      = f2bf(di * acc0[reg]);
            zr[16 + col] = f2bf(di * acc1[reg]);
            zr[32 + col] = f2bf(di * acc2[reg]);   // cols 40-47: Wb rows zero
            zr[48 + col] = 0;                      // cols 48-63: explicit zero
        }
    }
}

// ---- shared gather body: acc[8] += sum_{s in csr[beg..end)} zin[s] -----
// 8 lanes/node; each lane owns one 16B chunk of the 128B (one-line) row.
// Rows are src-ascending -> monotone walk of z (L2-friendly).
__device__ inline void gather_acc(
    const short8v* __restrict__ Z, const int* __restrict__ csr,
    int beg, int end, int c8, float acc[8]) {
    int j = beg;
    for (; j + 4 <= end; j += 4) {               // 4 gathers in flight
        int s0 = csr[j], s1 = csr[j+1], s2 = csr[j+2], s3 = csr[j+3];
        short8v v0 = Z[s0 * 8 + c8];
        short8v v1 = Z[s1 * 8 + c8];
        short8v v2 = Z[s2 * 8 + c8];
        short8v v3 = Z[s3 * 8 + c8];
#pragma unroll
        for (int k = 0; k < 8; ++k)
            acc[k] += (bf2f(v0[k]) + bf2f(v1[k])) + (bf2f(v2[k]) + bf2f(v3[k]));
    }
    for (; j < end; ++j) {
        short8v v = Z[csr[j] * 8 + c8];
#pragma unroll
        for (int k = 0; k < 8; ++k) acc[k] += bf2f(v[k]);
    }
}

// ---- hop1: z1 = bf16( dinv^2 .* (A z0) ), 8 lanes/node -----------------
__global__ __launch_bounds__(TPB) void k_hop1(
    const int* __restrict__ csr, const int* __restrict__ row_ptr,
    const float* __restrict__ dinv, const short* __restrict__ zin,
    short* __restrict__ zout, int N) {
    int t = blockIdx.x * TPB + threadIdx.x;
    int node = t >> 3;
    int c8 = t & 7;
    if (node >= N) return;
    const short8v* Z = reinterpret_cast<const short8v*>(zin);
    short8v sv = Z[node * 8 + c8];             // self-loop term
    float acc[8];
#pragma unroll
    for (int k = 0; k < 8; ++k) acc[k] = bf2f(sv[k]);
    gather_acc(Z, csr, row_ptr[node], row_ptr[node + 1], c8, acc);
    float dd = dinv[node];
    float sc = dd * dd;
    short8v o;
#pragma unroll
    for (int k = 0; k < 8; ++k) o[k] = f2bf(sc * acc[k]);
    reinterpret_cast<short8v*>(zout)[node * 8 + c8] = o;
}

// ---- hop2 fused with bias + log_softmax; 8 lanes/node, 8 nodes/wave ----
__global__ __launch_bounds__(TPB) void k_hop2_lsm(
    const int* __restrict__ csr, const int* __restrict__ row_ptr,
    const float* __restrict__ dinv, const short* __restrict__ zin,
    const float* __restrict__ bias, float* __restrict__ out, int N) {
    int t = blockIdx.x * TPB + threadIdx.x;
    int node = t >> 3;
    int c8 = t & 7;
    if (node >= N) return;
    const short8v* Z = reinterpret_cast<const short8v*>(zin);
    short8v sv = Z[node * 8 + c8];
    float acc[8];
#pragma unroll
    for (int k = 0; k < 8; ++k) acc[k] = bf2f(sv[k]);
    gather_acc(Z, csr, row_ptr[node], row_ptr[node + 1], c8, acc);
    float dd = dinv[node];

    float v[8];
    float lm = -1e30f;
    bool live = (c8 < 5);                      // cols 0..39 only
    if (live) {
#pragma unroll
        for (int k = 0; k < 8; ++k) {
            v[k] = dd * acc[k] + bias[c8 * 8 + k];
            lm = fmaxf(lm, v[k]);
        }
    }
    // butterfly over the 8-lane group (shfl_xor 1,2,4 stays in-group)
    float gm = lm;
    gm = fmaxf(gm, __shfl_xor(gm, 1));
    gm = fmaxf(gm, __shfl_xor(gm, 2));
    gm = fmaxf(gm, __shfl_xor(gm, 4));
    float ls = 0.f;
    if (live) {
#pragma unroll
        for (int k = 0; k < 8; ++k) ls += __expf(v[k] - gm);
    }
    ls += __shfl_xor(ls, 1);
    ls += __shfl_xor(ls, 2);
    ls += __shfl_xor(ls, 4);
    if (live) {
        float lse = gm + __logf(ls);
        float* op = out + (size_t)node * 40 + c8 * 8;
        *reinterpret_cast<float4*>(op)     = make_float4(v[0]-lse, v[1]-lse, v[2]-lse, v[3]-lse);
        *reinterpret_cast<float4*>(op + 4) = make_float4(v[4]-lse, v[5]-lse, v[6]-lse, v[7]-lse);
    }
}

extern "C" void kernel_launch(void* const* d_in, const int* in_sizes, int n_in,
                              void* d_out, int out_size, void* d_ws, size_t ws_size,
                              hipStream_t stream) {
    const float* x  = (const float*)d_in[0];
    const int*   ei = (const int*)d_in[1];
    const float* W  = (const float*)d_in[2];
    const float* b  = (const float*)d_in[3];
    float* out = (float*)d_out;

    const int N = in_sizes[0] / 512;     // 100000
    const int E = in_sizes[1] / 2;       // 3200000
    const int* src = ei;                 // edge_index[0]
    const int* dst = ei + E;             // edge_index[1]
    const int nb = (N + 255) >> 8;       // 391 buckets

    // workspace: z0 [N*64 bf16 = 12.8MB] | z1/pairs alias [12.8MB] | csr [E]
    //   | bcnt [nb] | boff [nb+1] | bcur [nb] | row_ptr [N+1] | dinv [N]
    //   | Wb [48*512 bf16]   (pairs dead before hop1 writes z1)
    short* z0      = (short*)d_ws;
    short* z1      = z0 + (size_t)N * ZS;
    int*   pairs   = (int*)z1;                 // alias: dead after k_sort
    int*   csr     = (int*)(z1 + (size_t)N * ZS);
    int*   bcnt    = csr + E;
    int*   boff    = bcnt + nb;
    int*   bcur    = boff + nb + 1;
    int*   row_ptr = bcur + nb;
    float* dinv    = (float*)(row_ptr + N + 1);
    short* Wb      = (short*)(dinv + N);

    int gT  = (E + ETILE - 1) / ETILE;   // 196 edge tiles
    int gM  = (N + 63) / 64;
    int gH  = (N * 8 + TPB - 1) / TPB;   // 3125

    k_wconv<<<(48 * 512) / TPB, TPB, 0, stream>>>(W, Wb, bcnt, nb);
    k_bhist<<<gT, TPB, 0, stream>>>(dst, bcnt, E, nb);
    k_boff<<<1, 512, 0, stream>>>(bcnt, boff, bcur, nb);
    k_part<<<gT, TPB, 0, stream>>>(src, dst, bcur, pairs, E, nb);
    k_sort<<<nb, TPB, 0, stream>>>(pairs, boff, csr, row_ptr, dinv, N, nb);

    k_matmul_mfma<<<gM, TPB, 0, stream>>>(x, Wb, dinv, z0, N);

    k_hop1<<<gH, TPB, 0, stream>>>(csr, row_ptr, dinv, z0, z1, N);
    k_hop2_lsm<<<gH, TPB, 0, stream>>>(csr, row_ptr, dinv, z1, b, out, N);
}

// Round 17
// 292.295 us; speedup vs baseline: 1.3296x; 1.0142x over previous
//
#include <hip/hip_runtime.h>
#include <hip/hip_bf16.h>

// SGConv (K=2) on MI355X.
// R4: MFMA matmul. R6: bucket build + counting sort -> CSR gather hops.
// R7: bf16 z-tables. R8/R9: gather unroll + fused hop2/log_softmax.
// R12: z rows padded to 128B (one line per gather). 310.7us.
// R15: sorted rows via register bitonic (hop L2 locality). 296.4us.
// R16: (a) k_bhist saves per-tile histograms -> k_part single-pass (no dst
//      re-read, no LDS-atomic hist); (b) packed bf16 cvt (v_cvt_pk_bf16_f32
//      via __float22bfloat162_rn) in matmul A-frag + hop1 store.

#define TPB 256
#define ETILE 16384                // edges per partition block
#define ZS 64                      // padded z row: 64 bf16 = 128 B
#define STASH 10240                // LDS sort stash (ints); bucket mean 8184

typedef __attribute__((ext_vector_type(8))) short short8v;   // bf16x8
typedef __attribute__((ext_vector_type(4))) float f32x4;

__device__ inline short f2bf(float f) {            // RNE f32->bf16 (scalar)
    unsigned u = __float_as_uint(f);
    unsigned r = (u + 0x7fffu + ((u >> 16) & 1u)) >> 16;
    return (short)r;
}
__device__ inline float bf2f(short s) {
    return __uint_as_float(((unsigned)(unsigned short)s) << 16);
}
__device__ inline unsigned pk2bf(float lo, float hi) {   // v_cvt_pk_bf16_f32
    float2 f2; f2.x = lo; f2.y = hi;
    __hip_bfloat162 p = __float22bfloat162_rn(f2);
    return *reinterpret_cast<unsigned*>(&p);
}

// ---- fully-unrolled 64-element bitonic sort on a register array --------
__device__ inline void bitonic64(int a[64]) {
#pragma unroll
    for (int k = 2; k <= 64; k <<= 1) {
#pragma unroll
        for (int j = k >> 1; j > 0; j >>= 1) {
#pragma unroll
            for (int i = 0; i < 64; ++i) {
                int l = i ^ j;
                if (l > i) {
                    int lo = min(a[i], a[l]);
                    int hi = max(a[i], a[l]);
                    bool up = ((i & k) == 0);
                    a[i] = up ? lo : hi;
                    a[l] = up ? hi : lo;
                }
            }
        }
    }
}

// ---- W -> Wb (48x512 bf16) and (block 0) zero bcnt ---------------------
__global__ void k_wconv(const float* __restrict__ W, short* __restrict__ Wb,
                        int* __restrict__ bcnt, int nb) {
    if (blockIdx.x == 0)
        for (int i = threadIdx.x; i < nb; i += TPB) bcnt[i] = 0;
    int idx = blockIdx.x * TPB + threadIdx.x;    // 0..24575
    int c = idx >> 9, k = idx & 511;
    float v = (c < 40) ? W[c * 512 + k] : 0.f;
    Wb[idx] = f2bf(v);
}

// ---- per-bucket edge histogram; saves per-tile hist to global ----------
__global__ __launch_bounds__(TPB) void k_bhist(
    const int* __restrict__ dst, int* __restrict__ bcnt,
    int* __restrict__ thist, int E, int nb) {
    __shared__ int h[512];
    int t = threadIdx.x;
    for (int i = t; i < nb; i += TPB) h[i] = 0;
    __syncthreads();
    int e0 = blockIdx.x * ETILE;
    int e1 = min(e0 + ETILE, E);
    for (int e = e0 + t; e < e1; e += TPB)
        atomicAdd(&h[dst[e] >> 8], 1);
    __syncthreads();
    for (int i = t; i < nb; i += TPB) {
        thist[blockIdx.x * 512 + i] = h[i];
        if (h[i]) atomicAdd(&bcnt[i], h[i]);
    }
}

// ---- 391-entry exclusive scan -> boff, bcur (single block) -------------
__global__ __launch_bounds__(512) void k_boff(
    const int* __restrict__ bcnt, int* __restrict__ boff,
    int* __restrict__ bcur, int nb) {
    __shared__ int s[512];
    int t = threadIdx.x;
    int own = (t < nb) ? bcnt[t] : 0;
    s[t] = own;
    __syncthreads();
    for (int off = 1; off < 512; off <<= 1) {
        int v = (t >= off) ? s[t - off] : 0;
        __syncthreads();
        s[t] += v;
        __syncthreads();
    }
    if (t < nb) {
        int ex = s[t] - own;
        boff[t] = ex;
        bcur[t] = ex;
        if (t == nb - 1) boff[nb] = s[t];
    }
}

// ---- bucket partition: single dst+src pass using saved tile hist -------
__global__ __launch_bounds__(TPB) void k_part(
    const int* __restrict__ src, const int* __restrict__ dst,
    const int* __restrict__ thist,
    int* __restrict__ bcur, int* __restrict__ pairs, int E, int nb) {
    __shared__ int base[512], lcur[512];
    int t = threadIdx.x;
    int bid = blockIdx.x;
    for (int i = t; i < nb; i += TPB) {
        int h = thist[bid * 512 + i];
        base[i] = h ? atomicAdd(&bcur[i], h) : 0;
        lcur[i] = 0;
    }
    __syncthreads();
    int e0 = bid * ETILE;
    int e1 = min(e0 + ETILE, E);
    for (int e = e0 + t; e < e1; e += TPB) {
        int d = dst[e];
        int b = d >> 8;
        int pos = base[b] + atomicAdd(&lcur[b], 1);
        pairs[pos] = ((d & 255) << 20) | src[e];   // src < 2^20
    }
}

// ---- per-bucket counting sort + per-row register-bitonic src sort ------
__global__ __launch_bounds__(TPB) void k_sort(
    const int* __restrict__ pairs, const int* __restrict__ boff,
    int* __restrict__ csr, int* __restrict__ row_ptr, float* __restrict__ dinv,
    int N, int nb) {
    __shared__ int B[STASH];
    __shared__ int hist[256], excl[256], lcur[256];
    int b = blockIdx.x, t = threadIdx.x;
    hist[t] = 0;
    __syncthreads();
    int beg = boff[b], end = boff[b + 1];
    int cnt = end - beg;
    for (int j = beg + t; j < end; j += TPB)
        atomicAdd(&hist[pairs[j] >> 20], 1);
    __syncthreads();
    int own = hist[t];
    excl[t] = own;
    __syncthreads();
    for (int off = 1; off < 256; off <<= 1) {
        int v = (t >= off) ? excl[t - off] : 0;
        __syncthreads();
        excl[t] += v;
        __syncthreads();
    }
    int node = (b << 8) + t;
    if (node < N) {
        row_ptr[node] = beg + excl[t] - own;   // global exclusive offset
        dinv[node] = rsqrtf((float)(own + 1)); // +1 self-loop
    }
    lcur[t] = 0;
    __syncthreads();
    if (cnt <= STASH) {
        for (int j = beg + t; j < end; j += TPB) {
            int u = pairs[j];
            int dl = u >> 20;
            int pos = (excl[dl] - hist[dl]) + atomicAdd(&lcur[dl], 1);
            B[pos] = u & 0xFFFFF;
        }
        __syncthreads();
        int s0 = excl[t] - own;
        if (own >= 2 && own <= 64) {
            int r[64];
#pragma unroll
            for (int i = 0; i < 64; ++i)
                r[i] = (i < own) ? B[s0 + i] : 0x7FFFFFFF;
            bitonic64(r);
#pragma unroll
            for (int i = 0; i < 64; ++i)
                if (i < own) B[s0 + i] = r[i];
        }
        __syncthreads();
        for (int j = t; j < cnt; j += TPB) csr[beg + j] = B[j];
    } else {
        for (int j = beg + t; j < end; j += TPB) {
            int u = pairs[j];
            int dl = u >> 20;
            int pos = beg + (excl[dl] - hist[dl]) + atomicAdd(&lcur[dl], 1);
            csr[pos] = u & 0xFFFFF;
        }
    }
    if (b == nb - 1 && t == 0) row_ptr[N] = end;
}

// ---- z0 = bf16( dinv .* (x @ W^T) ), row stride 64, cols 40..63 = 0 ----
__global__ __launch_bounds__(TPB) void k_matmul_mfma(
    const float* __restrict__ x, const short* __restrict__ Wb,
    const float* __restrict__ dinv, short* __restrict__ z, int N) {
    int wid  = threadIdx.x >> 6;
    int lane = threadIdx.x & 63;
    int rbase = blockIdx.x * 64 + wid * 16;
    if (rbase >= N) return;
    int arow   = rbase + (lane & 15);
    int aclamp = min(arow, N - 1);
    int koff   = (lane >> 4) * 8;
    const float* xrow = x + (size_t)aclamp * 512 + koff;
    const short* wb   = Wb + (lane & 15) * 512 + koff;

    f32x4 acc0 = {0.f,0.f,0.f,0.f}, acc1 = {0.f,0.f,0.f,0.f}, acc2 = {0.f,0.f,0.f,0.f};
    for (int ks = 0; ks < 16; ++ks) {
        int k0 = ks * 32;
        float4 f0 = *reinterpret_cast<const float4*>(xrow + k0);
        float4 f1 = *reinterpret_cast<const float4*>(xrow + k0 + 4);
        union { unsigned u[4]; short8v v; } A;
        A.u[0] = pk2bf(f0.x, f0.y);
        A.u[1] = pk2bf(f0.z, f0.w);
        A.u[2] = pk2bf(f1.x, f1.y);
        A.u[3] = pk2bf(f1.z, f1.w);
        short8v b0 = *reinterpret_cast<const short8v*>(wb + k0);
        short8v b1 = *reinterpret_cast<const short8v*>(wb + 16 * 512 + k0);
        short8v b2 = *reinterpret_cast<const short8v*>(wb + 32 * 512 + k0);
        acc0 = __builtin_amdgcn_mfma_f32_16x16x32_bf16(A.v, b0, acc0, 0, 0, 0);
        acc1 = __builtin_amdgcn_mfma_f32_16x16x32_bf16(A.v, b1, acc1, 0, 0, 0);
        acc2 = __builtin_amdgcn_mfma_f32_16x16x32_bf16(A.v, b2, acc2, 0, 0, 0);
    }
    int col = lane & 15;
    int rw  = rbase + (lane >> 4) * 4;
#pragma unroll
    for (int reg = 0; reg < 4; ++reg) {
        int r = rw + reg;
        if (r < N) {
            float di = dinv[r];
            short* zr = z + (size_t)r * ZS;
            zr[col]      = f2bf(di * acc0[reg]);
            zr[16 + col] = f2bf(di * acc1[reg]);
            zr[32 + col] = f2bf(di * acc2[reg]);   // cols 40-47: Wb rows zero
            zr[48 + col] = 0;                      // cols 48-63: explicit zero
        }
    }
}

// ---- shared gather body: acc[8] += sum_{s in csr[beg..end)} zin[s] -----
// 8 lanes/node; rows src-ascending -> monotone walk of z (L2-friendly).
__device__ inline void gather_acc(
    const short8v* __restrict__ Z, const int* __restrict__ csr,
    int beg, int end, int c8, float acc[8]) {
    int j = beg;
    for (; j + 4 <= end; j += 4) {               // 4 gathers in flight
        int s0 = csr[j], s1 = csr[j+1], s2 = csr[j+2], s3 = csr[j+3];
        short8v v0 = Z[s0 * 8 + c8];
        short8v v1 = Z[s1 * 8 + c8];
        short8v v2 = Z[s2 * 8 + c8];
        short8v v3 = Z[s3 * 8 + c8];
#pragma unroll
        for (int k = 0; k < 8; ++k)
            acc[k] += (bf2f(v0[k]) + bf2f(v1[k])) + (bf2f(v2[k]) + bf2f(v3[k]));
    }
    for (; j < end; ++j) {
        short8v v = Z[csr[j] * 8 + c8];
#pragma unroll
        for (int k = 0; k < 8; ++k) acc[k] += bf2f(v[k]);
    }
}

// ---- hop1: z1 = bf16( dinv^2 .* (A z0) ), 8 lanes/node -----------------
__global__ __launch_bounds__(TPB) void k_hop1(
    const int* __restrict__ csr, const int* __restrict__ row_ptr,
    const float* __restrict__ dinv, const short* __restrict__ zin,
    short* __restrict__ zout, int N) {
    int t = blockIdx.x * TPB + threadIdx.x;
    int node = t >> 3;
    int c8 = t & 7;
    if (node >= N) return;
    const short8v* Z = reinterpret_cast<const short8v*>(zin);
    short8v sv = Z[node * 8 + c8];             // self-loop term
    float acc[8];
#pragma unroll
    for (int k = 0; k < 8; ++k) acc[k] = bf2f(sv[k]);
    gather_acc(Z, csr, row_ptr[node], row_ptr[node + 1], c8, acc);
    float dd = dinv[node];
    float sc = dd * dd;
    union { unsigned u[4]; short8v v; } O;
    O.u[0] = pk2bf(sc * acc[0], sc * acc[1]);
    O.u[1] = pk2bf(sc * acc[2], sc * acc[3]);
    O.u[2] = pk2bf(sc * acc[4], sc * acc[5]);
    O.u[3] = pk2bf(sc * acc[6], sc * acc[7]);
    reinterpret_cast<short8v*>(zout)[node * 8 + c8] = O.v;
}

// ---- hop2 fused with bias + log_softmax; 8 lanes/node, 8 nodes/wave ----
__global__ __launch_bounds__(TPB) void k_hop2_lsm(
    const int* __restrict__ csr, const int* __restrict__ row_ptr,
    const float* __restrict__ dinv, const short* __restrict__ zin,
    const float* __restrict__ bias, float* __restrict__ out, int N) {
    int t = blockIdx.x * TPB + threadIdx.x;
    int node = t >> 3;
    int c8 = t & 7;
    if (node >= N) return;
    const short8v* Z = reinterpret_cast<const short8v*>(zin);
    short8v sv = Z[node * 8 + c8];
    float acc[8];
#pragma unroll
    for (int k = 0; k < 8; ++k) acc[k] = bf2f(sv[k]);
    gather_acc(Z, csr, row_ptr[node], row_ptr[node + 1], c8, acc);
    float dd = dinv[node];

    float v[8];
    float lm = -1e30f;
    bool live = (c8 < 5);                      // cols 0..39 only
    if (live) {
#pragma unroll
        for (int k = 0; k < 8; ++k) {
            v[k] = dd * acc[k] + bias[c8 * 8 + k];
            lm = fmaxf(lm, v[k]);
        }
    }
    // butterfly over the 8-lane group (shfl_xor 1,2,4 stays in-group)
    float gm = lm;
    gm = fmaxf(gm, __shfl_xor(gm, 1));
    gm = fmaxf(gm, __shfl_xor(gm, 2));
    gm = fmaxf(gm, __shfl_xor(gm, 4));
    float ls = 0.f;
    if (live) {
#pragma unroll
        for (int k = 0; k < 8; ++k) ls += __expf(v[k] - gm);
    }
    ls += __shfl_xor(ls, 1);
    ls += __shfl_xor(ls, 2);
    ls += __shfl_xor(ls, 4);
    if (live) {
        float lse = gm + __logf(ls);
        float* op = out + (size_t)node * 40 + c8 * 8;
        *reinterpret_cast<float4*>(op)     = make_float4(v[0]-lse, v[1]-lse, v[2]-lse, v[3]-lse);
        *reinterpret_cast<float4*>(op + 4) = make_float4(v[4]-lse, v[5]-lse, v[6]-lse, v[7]-lse);
    }
}

extern "C" void kernel_launch(void* const* d_in, const int* in_sizes, int n_in,
                              void* d_out, int out_size, void* d_ws, size_t ws_size,
                              hipStream_t stream) {
    const float* x  = (const float*)d_in[0];
    const int*   ei = (const int*)d_in[1];
    const float* W  = (const float*)d_in[2];
    const float* b  = (const float*)d_in[3];
    float* out = (float*)d_out;

    const int N = in_sizes[0] / 512;     // 100000
    const int E = in_sizes[1] / 2;       // 3200000
    const int* src = ei;                 // edge_index[0]
    const int* dst = ei + E;             // edge_index[1]
    const int nb = (N + 255) >> 8;       // 391 buckets

    // workspace: z0 [N*64 bf16 = 12.8MB] | z1/pairs alias [12.8MB] | csr [E]
    //   | bcnt [nb] | boff [nb+1] | bcur [nb] | row_ptr [N+1] | dinv [N]
    //   | Wb [48*512 bf16] | thist [gT*512]
    short* z0      = (short*)d_ws;
    short* z1      = z0 + (size_t)N * ZS;
    int*   pairs   = (int*)z1;                 // alias: dead after k_sort
    int*   csr     = (int*)(z1 + (size_t)N * ZS);
    int*   bcnt    = csr + E;
    int*   boff    = bcnt + nb;
    int*   bcur    = boff + nb + 1;
    int*   row_ptr = bcur + nb;
    float* dinv    = (float*)(row_ptr + N + 1);
    short* Wb      = (short*)(dinv + N);
    int*   thist   = (int*)(Wb + 48 * 512);

    int gT  = (E + ETILE - 1) / ETILE;   // 196 edge tiles
    int gM  = (N + 63) / 64;
    int gH  = (N * 8 + TPB - 1) / TPB;   // 3125

    k_wconv<<<(48 * 512) / TPB, TPB, 0, stream>>>(W, Wb, bcnt, nb);
    k_bhist<<<gT, TPB, 0, stream>>>(dst, bcnt, thist, E, nb);
    k_boff<<<1, 512, 0, stream>>>(bcnt, boff, bcur, nb);
    k_part<<<gT, TPB, 0, stream>>>(src, dst, thist, bcur, pairs, E, nb);
    k_sort<<<nb, TPB, 0, stream>>>(pairs, boff, csr, row_ptr, dinv, N, nb);

    k_matmul_mfma<<<gM, TPB, 0, stream>>>(x, Wb, dinv, z0, N);

    k_hop1<<<gH, TPB, 0, stream>>>(csr, row_ptr, dinv, z0, z1, N);
    k_hop2_lsm<<<gH, TPB, 0, stream>>>(csr, row_ptr, dinv, z1, b, out, N);
}